// Round 1
// baseline (1095.268 us; speedup 1.0000x reference)
//
#include <hip/hip_runtime.h>

#define N_PTS 524288

typedef __attribute__((ext_vector_type(8))) short bf16x8;
typedef __attribute__((ext_vector_type(4))) short bf16x4;
typedef __attribute__((ext_vector_type(4))) float f32x4;

// float -> bf16 (round-to-nearest-even), bit pattern in ushort
__device__ __forceinline__ unsigned short f2bf(float f) {
    unsigned u = __builtin_bit_cast(unsigned, f);
    u = (u + 0x7FFFu + ((u >> 16) & 1u)) >> 16;
    return (unsigned short)u;
}

__device__ __forceinline__ float encf(float v, float f) {
    float t = v * f;
    return 2.0f * (t - floorf(t)) - 1.0f;   // jnp: 2*(f*x % 1) - 1
}

// align_corners=True trilinear gather of a [4, R, R, R] grid at p in [-1,1]^3
template <int R>
__device__ __forceinline__ float4 trilerp4(const float* __restrict__ g,
                                           float px, float py, float pz) {
    constexpr float S = 0.5f * (float)(R - 1);
    float cx = (px + 1.0f) * S;
    float cy = (py + 1.0f) * S;
    float cz = (pz + 1.0f) * S;
    float fx0 = floorf(cx), fy0 = floorf(cy), fz0 = floorf(cz);
    float fx = cx - fx0, fy = cy - fy0, fz = cz - fz0;
    int ix0 = min(max((int)fx0, 0), R - 1);
    int iy0 = min(max((int)fy0, 0), R - 1);
    int iz0 = min(max((int)fz0, 0), R - 1);
    int dx = (ix0 < R - 1) ? 1 : 0;
    int dy = (iy0 < R - 1) ? R : 0;
    int dz = (iz0 < R - 1) ? R * R : 0;
    int base = iz0 * (R * R) + iy0 * R + ix0;

    float gx0 = 1.0f - fx, gy0 = 1.0f - fy, gz0 = 1.0f - fz;
    float w00 = gz0 * gy0, w01 = gz0 * fy, w10 = fz * gy0, w11 = fz * fy;
    float w000 = w00 * gx0, w001 = w00 * fx;
    float w010 = w01 * gx0, w011 = w01 * fx;
    float w100 = w10 * gx0, w101 = w10 * fx;
    float w110 = w11 * gx0, w111 = w11 * fx;

    float4 out;
    float r[4];
#pragma unroll
    for (int c = 0; c < 4; ++c) {
        const float* gc = g + (size_t)c * (R * R * R);
        float v000 = gc[base];
        float v001 = gc[base + dx];
        float v010 = gc[base + dy];
        float v011 = gc[base + dy + dx];
        float v100 = gc[base + dz];
        float v101 = gc[base + dz + dx];
        float v110 = gc[base + dz + dy];
        float v111 = gc[base + dz + dy + dx];
        r[c] = v000 * w000 + v001 * w001 + v010 * w010 + v011 * w011 +
               v100 * w100 + v101 * w101 + v110 * w110 + v111 * w111;
    }
    out.x = r[0]; out.y = r[1]; out.z = r[2]; out.w = r[3];
    return out;
}

// ---------------- kernel 1: features -> bf16 [N,16] ----------------
__global__ __launch_bounds__(256) void feat_kernel(
    const float* __restrict__ x,
    const float* __restrict__ g0, const float* __restrict__ g1,
    const float* __restrict__ g2, const float* __restrict__ g3,
    const float* __restrict__ coef,
    unsigned short* __restrict__ feats) {
    int i = blockIdx.x * 256 + threadIdx.x;
    float px = x[3 * i + 0], py = x[3 * i + 1], pz = x[3 * i + 2];

    float4 cf = trilerp4<64>(coef, px, py, pz);

    float o[16];
    {
        float4 t = trilerp4<32>(g0, encf(px, 1.f), encf(py, 1.f), encf(pz, 1.f));
        o[0] = t.x * cf.x; o[1] = t.y * cf.x; o[2] = t.z * cf.x; o[3] = t.w * cf.x;
    }
    {
        float4 t = trilerp4<64>(g1, encf(px, 2.f), encf(py, 2.f), encf(pz, 2.f));
        o[4] = t.x * cf.y; o[5] = t.y * cf.y; o[6] = t.z * cf.y; o[7] = t.w * cf.y;
    }
    {
        float4 t = trilerp4<128>(g2, encf(px, 4.f), encf(py, 4.f), encf(pz, 4.f));
        o[8] = t.x * cf.z; o[9] = t.y * cf.z; o[10] = t.z * cf.z; o[11] = t.w * cf.z;
    }
    {
        float4 t = trilerp4<256>(g3, encf(px, 8.f), encf(py, 8.f), encf(pz, 8.f));
        o[12] = t.x * cf.w; o[13] = t.y * cf.w; o[14] = t.z * cf.w; o[15] = t.w * cf.w;
    }

    bf16x8 lo, hi;
#pragma unroll
    for (int j = 0; j < 8; ++j) {
        lo[j] = (short)f2bf(o[j]);
        hi[j] = (short)f2bf(o[8 + j]);
    }
    bf16x8* dst = (bf16x8*)(feats + (size_t)i * 16);
    dst[0] = lo;
    dst[1] = hi;
}

// ---------------- kernel 2: weight prep (transpose + bf16) ----------------
// wt layout: WT0 [128][32] (k>=16 zero-padded), then WT1..WT6 each [128][128];
// WT[n][k] = W[k][n].  biases: [7][128] fp32.
__global__ __launch_bounds__(256) void prep_kernel(
    const float* __restrict__ W0, const float* __restrict__ W1,
    const float* __restrict__ W2, const float* __restrict__ W3,
    const float* __restrict__ W4, const float* __restrict__ W5,
    const float* __restrict__ W6,
    const float* __restrict__ B0, const float* __restrict__ B1,
    const float* __restrict__ B2, const float* __restrict__ B3,
    const float* __restrict__ B4, const float* __restrict__ B5,
    const float* __restrict__ B6,
    unsigned short* __restrict__ wt, float* __restrict__ biases) {
    int tid = blockIdx.x * 256 + threadIdx.x;
    if (tid < 4096) {
        int n = tid >> 5, k = tid & 31;
        float v = (k < 16) ? W0[k * 128 + n] : 0.0f;
        wt[tid] = f2bf(v);
    } else if (tid < 102400) {
        int e = tid - 4096;
        int l = e >> 14;  // 0..5 -> layer l+1
        int r = e & 16383;
        int n = r >> 7, k = r & 127;
        const float* W = (l == 0) ? W1 : (l == 1) ? W2 : (l == 2) ? W3
                        : (l == 3) ? W4 : (l == 4) ? W5 : W6;
        wt[tid] = f2bf(W[k * 128 + n]);
    } else if (tid < 102400 + 896) {
        int e = tid - 102400;
        int l = e >> 7;
        const float* B = (l == 0) ? B0 : (l == 1) ? B1 : (l == 2) ? B2
                        : (l == 3) ? B3 : (l == 4) ? B4 : (l == 5) ? B5 : B6;
        biases[e] = B[e & 127];
    }
}

// ---------------- kernel 3: fused 7-layer MLP ----------------
// 128 rows/block, 4 waves in 2x2, 64x64 tile per wave, mfma_f32_16x16x32_bf16.
// Operands swapped (A = WT-frag, B = H-frag) so D is transposed: lane holds
// col m = lane&15, rows n = quad*4+reg (4 consecutive n) -> b64 LDS epilogue
// writes / float4 global stores.
#define LDS_STRIDE 136  // 128 + 8: bank-balanced for b128 frag reads

__global__ __launch_bounds__(256, 2) void mlp_kernel(
    const unsigned short* __restrict__ feats,
    const unsigned short* __restrict__ wt,
    const float* __restrict__ biases,
    float* __restrict__ out) {
    __shared__ __attribute__((aligned(16))) unsigned short Hs[128 * LDS_STRIDE];
    __shared__ __attribute__((aligned(16))) unsigned short Ws[128 * LDS_STRIDE];
    __shared__ float Bs[128];

    const int t = threadIdx.x;
    const int lane = t & 63;
    const int w = t >> 6;
    const int wr = (w >> 1) * 64;  // row base of this wave's tile
    const int wc = (w & 1) * 64;   // col base
    const int lr = lane & 15;
    const int q = lane >> 4;

    // stage H0: feats [128 rows x 16] + zero-pad k=16..31
    {
        int row = t >> 1, half = t & 1;
        size_t grow = (size_t)blockIdx.x * 128 + row;
        bf16x8 v = ((const bf16x8*)(feats + grow * 16))[half];
        *(bf16x8*)(&Hs[row * LDS_STRIDE + half * 8]) = v;
        bf16x8 z = (bf16x8)0;
        *(bf16x8*)(&Hs[row * LDS_STRIDE + 16 + half * 8]) = z;
    }

    for (int l = 0; l < 7; ++l) {
        // stage WT_l into Ws (b128 copies, bank-balanced writes)
        {
            const unsigned short* src = wt + ((l == 0) ? 0 : (4096 + (l - 1) * 16384));
            const int nelem = (l == 0) ? 4096 : 16384;
            const int kbits = (l == 0) ? 5 : 7;
            const int kmask = (1 << kbits) - 1;
            for (int idx = t * 8; idx < nelem; idx += 2048) {
                bf16x8 v = *(const bf16x8*)(src + idx);
                int n = idx >> kbits, k = idx & kmask;
                *(bf16x8*)(&Ws[n * LDS_STRIDE + k]) = v;
            }
            if (t < 128) Bs[t] = biases[l * 128 + t];
        }
        __syncthreads();

        f32x4 acc[4][4] = {};
        const int K = (l == 0) ? 32 : 128;
        for (int kk = 0; kk < K; kk += 32) {
            bf16x8 hf[4], wf[4];
#pragma unroll
            for (int mi = 0; mi < 4; ++mi)
                hf[mi] = *(const bf16x8*)(&Hs[(wr + mi * 16 + lr) * LDS_STRIDE + kk + q * 8]);
#pragma unroll
            for (int ni = 0; ni < 4; ++ni)
                wf[ni] = *(const bf16x8*)(&Ws[(wc + ni * 16 + lr) * LDS_STRIDE + kk + q * 8]);
#pragma unroll
            for (int ni = 0; ni < 4; ++ni)
#pragma unroll
                for (int mi = 0; mi < 4; ++mi)
                    acc[ni][mi] = __builtin_amdgcn_mfma_f32_16x16x32_bf16(
                        wf[ni], hf[mi], acc[ni][mi], 0, 0, 0);
        }
        __syncthreads();

        if (l < 6) {
            // epilogue: h = relu(acc + b) -> Hs (transposed D: 4 consecutive k per lane)
#pragma unroll
            for (int ni = 0; ni < 4; ++ni) {
                int n0 = wc + ni * 16 + q * 4;
                float4 bv = *(const float4*)(&Bs[n0]);
#pragma unroll
                for (int mi = 0; mi < 4; ++mi) {
                    f32x4 a = acc[ni][mi];
                    bf16x4 p;
                    p[0] = (short)f2bf(fmaxf(a[0] + bv.x, 0.0f));
                    p[1] = (short)f2bf(fmaxf(a[1] + bv.y, 0.0f));
                    p[2] = (short)f2bf(fmaxf(a[2] + bv.z, 0.0f));
                    p[3] = (short)f2bf(fmaxf(a[3] + bv.w, 0.0f));
                    *(bf16x4*)(&Hs[(wr + mi * 16 + lr) * LDS_STRIDE + n0]) = p;
                }
            }
        } else {
            // final layer: no relu, fp32 float4 stores
            size_t rowbase = (size_t)blockIdx.x * 128;
#pragma unroll
            for (int ni = 0; ni < 4; ++ni) {
                int n0 = wc + ni * 16 + q * 4;
                float4 bv = *(const float4*)(&Bs[n0]);
#pragma unroll
                for (int mi = 0; mi < 4; ++mi) {
                    f32x4 a = acc[ni][mi];
                    int m = wr + mi * 16 + lr;
                    float4 v = make_float4(a[0] + bv.x, a[1] + bv.y,
                                           a[2] + bv.z, a[3] + bv.w);
                    *(float4*)(&out[(rowbase + m) * 128 + n0]) = v;
                }
            }
        }
    }
}

extern "C" void kernel_launch(void* const* d_in, const int* in_sizes, int n_in,
                              void* d_out, int out_size, void* d_ws, size_t ws_size,
                              hipStream_t stream) {
    const float* x = (const float*)d_in[0];
    const float* g0 = (const float*)d_in[1];
    const float* g1 = (const float*)d_in[2];
    const float* g2 = (const float*)d_in[3];
    const float* g3 = (const float*)d_in[4];
    const float* coef = (const float*)d_in[5];
    const float* W[7];
    const float* B[7];
    for (int j = 0; j < 7; ++j) {
        W[j] = (const float*)d_in[6 + 2 * j];
        B[j] = (const float*)d_in[7 + 2 * j];
    }

    char* ws = (char*)d_ws;
    unsigned short* feats = (unsigned short*)ws;                       // 16 MB
    unsigned short* wt = (unsigned short*)(ws + 16777216);             // 200 KB
    float* biases = (float*)(ws + 16777216 + 204800);                  // 3.5 KB

    feat_kernel<<<N_PTS / 256, 256, 0, stream>>>(x, g0, g1, g2, g3, coef, feats);
    prep_kernel<<<404, 256, 0, stream>>>(W[0], W[1], W[2], W[3], W[4], W[5], W[6],
                                         B[0], B[1], B[2], B[3], B[4], B[5], B[6],
                                         wt, biases);
    mlp_kernel<<<N_PTS / 128, 256, 0, stream>>>(feats, wt, biases, (float*)d_out);
}

// Round 2
// 907.523 us; speedup vs baseline: 1.2069x; 1.2069x over previous
//
#include <hip/hip_runtime.h>

#define N_PTS 524288

typedef __attribute__((ext_vector_type(8))) short bf16x8;
typedef __attribute__((ext_vector_type(4))) short bf16x4;
typedef __attribute__((ext_vector_type(4))) float f32x4;

// float -> bf16 (round-to-nearest-even), bit pattern in ushort
__device__ __forceinline__ unsigned short f2bf(float f) {
    unsigned u = __builtin_bit_cast(unsigned, f);
    u = (u + 0x7FFFu + ((u >> 16) & 1u)) >> 16;
    return (unsigned short)u;
}

__device__ __forceinline__ float encf(float v, float f) {
    float t = v * f;
    return 2.0f * (t - floorf(t)) - 1.0f;   // jnp: 2*(f*x % 1) - 1
}

// ---------------- channel-interleave: [4][R^3] -> [R^3][4] ----------------
template <int R>
__global__ __launch_bounds__(256) void ileave_kernel(const float* __restrict__ g,
                                                     float* __restrict__ gi) {
    constexpr int V = R * R * R;
    int idx = blockIdx.x * 256 + threadIdx.x;
    float4 v = make_float4(g[idx], g[idx + V], g[idx + 2 * V], g[idx + 3 * V]);
    *(float4*)(&gi[(size_t)idx * 4]) = v;
}

// trilerp over channel-interleaved grid: one float4 per corner
template <int R>
__device__ __forceinline__ float4 trilerp4i(const float* __restrict__ gi,
                                            float px, float py, float pz) {
    constexpr float S = 0.5f * (float)(R - 1);
    float cx = (px + 1.0f) * S;
    float cy = (py + 1.0f) * S;
    float cz = (pz + 1.0f) * S;
    float fx0 = floorf(cx), fy0 = floorf(cy), fz0 = floorf(cz);
    float fx = cx - fx0, fy = cy - fy0, fz = cz - fz0;
    int ix0 = min(max((int)fx0, 0), R - 1);
    int iy0 = min(max((int)fy0, 0), R - 1);
    int iz0 = min(max((int)fz0, 0), R - 1);
    int dx = (ix0 < R - 1) ? 4 : 0;           // offsets in floats (4 ch)
    int dy = (iy0 < R - 1) ? 4 * R : 0;
    int dz = (iz0 < R - 1) ? 4 * R * R : 0;
    const float* p = gi + 4 * ((size_t)iz0 * (R * R) + iy0 * R + ix0);

    float4 v000 = *(const float4*)(p);
    float4 v001 = *(const float4*)(p + dx);
    float4 v010 = *(const float4*)(p + dy);
    float4 v011 = *(const float4*)(p + dy + dx);
    float4 v100 = *(const float4*)(p + dz);
    float4 v101 = *(const float4*)(p + dz + dx);
    float4 v110 = *(const float4*)(p + dz + dy);
    float4 v111 = *(const float4*)(p + dz + dy + dx);

    float gx0 = 1.0f - fx, gy0 = 1.0f - fy, gz0 = 1.0f - fz;
    float w00 = gz0 * gy0, w01 = gz0 * fy, w10 = fz * gy0, w11 = fz * fy;
    float w000 = w00 * gx0, w001 = w00 * fx;
    float w010 = w01 * gx0, w011 = w01 * fx;
    float w100 = w10 * gx0, w101 = w10 * fx;
    float w110 = w11 * gx0, w111 = w11 * fx;

    float4 r;
    r.x = v000.x * w000 + v001.x * w001 + v010.x * w010 + v011.x * w011 +
          v100.x * w100 + v101.x * w101 + v110.x * w110 + v111.x * w111;
    r.y = v000.y * w000 + v001.y * w001 + v010.y * w010 + v011.y * w011 +
          v100.y * w100 + v101.y * w101 + v110.y * w110 + v111.y * w111;
    r.z = v000.z * w000 + v001.z * w001 + v010.z * w010 + v011.z * w011 +
          v100.z * w100 + v101.z * w101 + v110.z * w110 + v111.z * w111;
    r.w = v000.w * w000 + v001.w * w001 + v010.w * w010 + v011.w * w011 +
          v100.w * w100 + v101.w * w101 + v110.w * w110 + v111.w * w111;
    return r;
}

// strided (original-layout) trilerp — fallback path only
template <int R>
__device__ __forceinline__ float4 trilerp4s(const float* __restrict__ g,
                                            float px, float py, float pz) {
    constexpr float S = 0.5f * (float)(R - 1);
    float cx = (px + 1.0f) * S;
    float cy = (py + 1.0f) * S;
    float cz = (pz + 1.0f) * S;
    float fx0 = floorf(cx), fy0 = floorf(cy), fz0 = floorf(cz);
    float fx = cx - fx0, fy = cy - fy0, fz = cz - fz0;
    int ix0 = min(max((int)fx0, 0), R - 1);
    int iy0 = min(max((int)fy0, 0), R - 1);
    int iz0 = min(max((int)fz0, 0), R - 1);
    int dx = (ix0 < R - 1) ? 1 : 0;
    int dy = (iy0 < R - 1) ? R : 0;
    int dz = (iz0 < R - 1) ? R * R : 0;
    int base = iz0 * (R * R) + iy0 * R + ix0;

    float gx0 = 1.0f - fx, gy0 = 1.0f - fy, gz0 = 1.0f - fz;
    float w00 = gz0 * gy0, w01 = gz0 * fy, w10 = fz * gy0, w11 = fz * fy;
    float w000 = w00 * gx0, w001 = w00 * fx;
    float w010 = w01 * gx0, w011 = w01 * fx;
    float w100 = w10 * gx0, w101 = w10 * fx;
    float w110 = w11 * gx0, w111 = w11 * fx;

    float4 out;
    float r[4];
#pragma unroll
    for (int c = 0; c < 4; ++c) {
        const float* gc = g + (size_t)c * (R * R * R);
        r[c] = gc[base] * w000 + gc[base + dx] * w001 + gc[base + dy] * w010 +
               gc[base + dy + dx] * w011 + gc[base + dz] * w100 +
               gc[base + dz + dx] * w101 + gc[base + dz + dy] * w110 +
               gc[base + dz + dy + dx] * w111;
    }
    out.x = r[0]; out.y = r[1]; out.z = r[2]; out.w = r[3];
    return out;
}

// ---------------- kernel 1: features -> bf16 [N,16] ----------------
__global__ __launch_bounds__(256) void feat_i_kernel(
    const float* __restrict__ x,
    const float* __restrict__ g0i, const float* __restrict__ g1i,
    const float* __restrict__ g2i, const float* __restrict__ g3i,
    const float* __restrict__ coefi,
    unsigned short* __restrict__ feats) {
    int i = blockIdx.x * 256 + threadIdx.x;
    float px = x[3 * i + 0], py = x[3 * i + 1], pz = x[3 * i + 2];

    float4 cf = trilerp4i<64>(coefi, px, py, pz);
    float4 t0 = trilerp4i<32>(g0i, encf(px, 1.f), encf(py, 1.f), encf(pz, 1.f));
    float4 t1 = trilerp4i<64>(g1i, encf(px, 2.f), encf(py, 2.f), encf(pz, 2.f));
    float4 t2 = trilerp4i<128>(g2i, encf(px, 4.f), encf(py, 4.f), encf(pz, 4.f));
    float4 t3 = trilerp4i<256>(g3i, encf(px, 8.f), encf(py, 8.f), encf(pz, 8.f));

    float o[16];
    o[0] = t0.x * cf.x; o[1] = t0.y * cf.x; o[2] = t0.z * cf.x; o[3] = t0.w * cf.x;
    o[4] = t1.x * cf.y; o[5] = t1.y * cf.y; o[6] = t1.z * cf.y; o[7] = t1.w * cf.y;
    o[8] = t2.x * cf.z; o[9] = t2.y * cf.z; o[10] = t2.z * cf.z; o[11] = t2.w * cf.z;
    o[12] = t3.x * cf.w; o[13] = t3.y * cf.w; o[14] = t3.z * cf.w; o[15] = t3.w * cf.w;

    bf16x8 lo, hi;
#pragma unroll
    for (int j = 0; j < 8; ++j) {
        lo[j] = (short)f2bf(o[j]);
        hi[j] = (short)f2bf(o[8 + j]);
    }
    bf16x8* dst = (bf16x8*)(feats + (size_t)i * 16);
    dst[0] = lo;
    dst[1] = hi;
}

// fallback (workspace too small for interleaved grids)
__global__ __launch_bounds__(256) void feat_s_kernel(
    const float* __restrict__ x,
    const float* __restrict__ g0, const float* __restrict__ g1,
    const float* __restrict__ g2, const float* __restrict__ g3,
    const float* __restrict__ coef,
    unsigned short* __restrict__ feats) {
    int i = blockIdx.x * 256 + threadIdx.x;
    float px = x[3 * i + 0], py = x[3 * i + 1], pz = x[3 * i + 2];

    float4 cf = trilerp4s<64>(coef, px, py, pz);
    float4 t0 = trilerp4s<32>(g0, encf(px, 1.f), encf(py, 1.f), encf(pz, 1.f));
    float4 t1 = trilerp4s<64>(g1, encf(px, 2.f), encf(py, 2.f), encf(pz, 2.f));
    float4 t2 = trilerp4s<128>(g2, encf(px, 4.f), encf(py, 4.f), encf(pz, 4.f));
    float4 t3 = trilerp4s<256>(g3, encf(px, 8.f), encf(py, 8.f), encf(pz, 8.f));

    float o[16];
    o[0] = t0.x * cf.x; o[1] = t0.y * cf.x; o[2] = t0.z * cf.x; o[3] = t0.w * cf.x;
    o[4] = t1.x * cf.y; o[5] = t1.y * cf.y; o[6] = t1.z * cf.y; o[7] = t1.w * cf.y;
    o[8] = t2.x * cf.z; o[9] = t2.y * cf.z; o[10] = t2.z * cf.z; o[11] = t2.w * cf.z;
    o[12] = t3.x * cf.w; o[13] = t3.y * cf.w; o[14] = t3.z * cf.w; o[15] = t3.w * cf.w;

    bf16x8 lo, hi;
#pragma unroll
    for (int j = 0; j < 8; ++j) {
        lo[j] = (short)f2bf(o[j]);
        hi[j] = (short)f2bf(o[8 + j]);
    }
    bf16x8* dst = (bf16x8*)(feats + (size_t)i * 16);
    dst[0] = lo;
    dst[1] = hi;
}

// ---------------- kernel 2: weight prep -> MFMA-fragment order ----------------
// For layer l, element index e = (((kk*2 + wcol)*4 + ni)*64 + lane)*8 + j maps to
// WT[n][k] with n = wcol*64 + ni*16 + (lane&15), k = kk*32 + (lane>>4)*8 + j.
// Layer offsets: l==0 -> 0 (4096 elems, K padded 16->32), l>=1 -> 4096+(l-1)*16384.
// biases: [7][128] fp32 after the 102400 weight elems.
__global__ __launch_bounds__(256) void prep_kernel(
    const float* __restrict__ W0, const float* __restrict__ W1,
    const float* __restrict__ W2, const float* __restrict__ W3,
    const float* __restrict__ W4, const float* __restrict__ W5,
    const float* __restrict__ W6,
    const float* __restrict__ B0, const float* __restrict__ B1,
    const float* __restrict__ B2, const float* __restrict__ B3,
    const float* __restrict__ B4, const float* __restrict__ B5,
    const float* __restrict__ B6,
    unsigned short* __restrict__ wt, float* __restrict__ biases) {
    int tid = blockIdx.x * 256 + threadIdx.x;
    if (tid < 102400) {
        int l, e;
        if (tid < 4096) { l = 0; e = tid; }
        else { l = 1 + (tid - 4096) / 16384; e = (tid - 4096) % 16384; }
        int j = e & 7;
        int lane = (e >> 3) & 63;
        int ni = (e >> 9) & 3;
        int wcol = (e >> 11) & 1;
        int kk = e >> 12;
        int n = wcol * 64 + ni * 16 + (lane & 15);
        int k = kk * 32 + (lane >> 4) * 8 + j;
        const float* W = (l == 0) ? W0 : (l == 1) ? W1 : (l == 2) ? W2
                        : (l == 3) ? W3 : (l == 4) ? W4 : (l == 5) ? W5 : W6;
        int din = (l == 0) ? 16 : 128;
        float v = (k < din) ? W[k * 128 + n] : 0.0f;
        wt[tid] = f2bf(v);
    } else if (tid < 102400 + 896) {
        int e = tid - 102400;
        int l = e >> 7;
        const float* B = (l == 0) ? B0 : (l == 1) ? B1 : (l == 2) ? B2
                        : (l == 3) ? B3 : (l == 4) ? B4 : (l == 5) ? B5 : B6;
        biases[e] = B[e & 127];
    }
}

// ---------------- kernel 3: fused 7-layer MLP ----------------
// 256 rows/block, 8 waves in 4x2 (64x64 tile/wave), mfma_f32_16x16x32_bf16.
// Weights are read per-lane from global in fragment order (L2-hot, coalesced);
// only H lives in LDS. Operands swapped (A=W-frag, B=H-frag) -> transposed D:
// lane holds cols n0..n0+3 (b64 LDS epilogue / float4 global stores).
#define LDS_STRIDE 136  // 128+8 shorts: bank-balanced b128 frag reads
#define MROWS 256

__global__ __launch_bounds__(512, 4) void mlp_kernel(
    const unsigned short* __restrict__ feats,
    const unsigned short* __restrict__ wt,
    const float* __restrict__ biases,
    float* __restrict__ out) {
    __shared__ __attribute__((aligned(16))) unsigned short Hs[MROWS * LDS_STRIDE];

    const int t = threadIdx.x;
    const int lane = t & 63;
    const int w = t >> 6;
    const int wr = (w >> 1) * 64;   // row base of this wave's tile
    const int wc = (w & 1) * 64;    // col base
    const int wcol = w & 1;
    const int lr = lane & 15;
    const int q = lane >> 4;

    // stage H0: feats [256 rows x 16] + zero-pad k=16..31
    {
        int row = t >> 1, half = t & 1;
        size_t grow = (size_t)blockIdx.x * MROWS + row;
        bf16x8 v = ((const bf16x8*)(feats + grow * 16))[half];
        *(bf16x8*)(&Hs[row * LDS_STRIDE + half * 8]) = v;
        bf16x8 z = (bf16x8)0;
        *(bf16x8*)(&Hs[row * LDS_STRIDE + 16 + half * 8]) = z;
    }
    __syncthreads();

    for (int l = 0; l < 7; ++l) {
        const unsigned short* wl = wt + ((l == 0) ? 0 : (4096 + (l - 1) * 16384));
        f32x4 acc[4][4] = {};

        if (l == 0) {
            bf16x8 hf[4], wf[4];
#pragma unroll
            for (int mi = 0; mi < 4; ++mi)
                hf[mi] = *(const bf16x8*)(&Hs[(wr + mi * 16 + lr) * LDS_STRIDE + q * 8]);
            const unsigned short* wb = wl + wcol * 2048 + lane * 8;
#pragma unroll
            for (int ni = 0; ni < 4; ++ni)
                wf[ni] = *(const bf16x8*)(wb + ni * 512);
#pragma unroll
            for (int ni = 0; ni < 4; ++ni)
#pragma unroll
                for (int mi = 0; mi < 4; ++mi)
                    acc[ni][mi] = __builtin_amdgcn_mfma_f32_16x16x32_bf16(
                        wf[ni], hf[mi], acc[ni][mi], 0, 0, 0);
        } else {
#pragma unroll
            for (int kk = 0; kk < 4; ++kk) {
                bf16x8 hf[4], wf[4];
#pragma unroll
                for (int mi = 0; mi < 4; ++mi)
                    hf[mi] = *(const bf16x8*)(
                        &Hs[(wr + mi * 16 + lr) * LDS_STRIDE + kk * 32 + q * 8]);
                const unsigned short* wb = wl + (kk * 2 + wcol) * 2048 + lane * 8;
#pragma unroll
                for (int ni = 0; ni < 4; ++ni)
                    wf[ni] = *(const bf16x8*)(wb + ni * 512);
#pragma unroll
                for (int ni = 0; ni < 4; ++ni)
#pragma unroll
                    for (int mi = 0; mi < 4; ++mi)
                        acc[ni][mi] = __builtin_amdgcn_mfma_f32_16x16x32_bf16(
                            wf[ni], hf[mi], acc[ni][mi], 0, 0, 0);
            }
        }
        __syncthreads();  // all reads of H_l complete

        if (l < 6) {
#pragma unroll
            for (int ni = 0; ni < 4; ++ni) {
                int n0 = wc + ni * 16 + q * 4;
                float4 bv = *(const float4*)(&biases[l * 128 + n0]);
#pragma unroll
                for (int mi = 0; mi < 4; ++mi) {
                    f32x4 a = acc[ni][mi];
                    bf16x4 p;
                    p[0] = (short)f2bf(fmaxf(a[0] + bv.x, 0.0f));
                    p[1] = (short)f2bf(fmaxf(a[1] + bv.y, 0.0f));
                    p[2] = (short)f2bf(fmaxf(a[2] + bv.z, 0.0f));
                    p[3] = (short)f2bf(fmaxf(a[3] + bv.w, 0.0f));
                    *(bf16x4*)(&Hs[(wr + mi * 16 + lr) * LDS_STRIDE + n0]) = p;
                }
            }
            __syncthreads();  // H_{l+1} visible
        } else {
            size_t rowbase = (size_t)blockIdx.x * MROWS;
#pragma unroll
            for (int ni = 0; ni < 4; ++ni) {
                int n0 = wc + ni * 16 + q * 4;
                float4 bv = *(const float4*)(&biases[l * 128 + n0]);
#pragma unroll
                for (int mi = 0; mi < 4; ++mi) {
                    f32x4 a = acc[ni][mi];
                    int m = wr + mi * 16 + lr;
                    float4 v = make_float4(a[0] + bv.x, a[1] + bv.y,
                                           a[2] + bv.z, a[3] + bv.w);
                    *(float4*)(&out[(rowbase + m) * 128 + n0]) = v;
                }
            }
        }
    }
}

extern "C" void kernel_launch(void* const* d_in, const int* in_sizes, int n_in,
                              void* d_out, int out_size, void* d_ws, size_t ws_size,
                              hipStream_t stream) {
    const float* x = (const float*)d_in[0];
    const float* g0 = (const float*)d_in[1];
    const float* g1 = (const float*)d_in[2];
    const float* g2 = (const float*)d_in[3];
    const float* g3 = (const float*)d_in[4];
    const float* coef = (const float*)d_in[5];
    const float* W[7];
    const float* B[7];
    for (int j = 0; j < 7; ++j) {
        W[j] = (const float*)d_in[6 + 2 * j];
        B[j] = (const float*)d_in[7 + 2 * j];
    }

    // workspace layout (bytes):
    //   feats   @ 0         16,777,216   (bf16 [N][16])
    //   wt      @ 16777216     204,800   (bf16 fragment-order weights)
    //   biases  @ 16982016       3,584   (fp32 [7][128])
    //   coefi   @ 16985600   4,194,304   (fp32 [64^3][4])
    //   g0i     @ 21179904     524,288
    //   g1i     @ 21704192   4,194,304
    //   g2i     @ 25898496  33,554,432   -> end 59,452,928
    // g3i (fp32 [256^3][4] = 268,435,456 B) aliases d_out (== out_size*4),
    // safe: ileave -> feat(read) -> mlp(write) are stream-ordered.
    char* ws = (char*)d_ws;
    unsigned short* feats = (unsigned short*)ws;
    unsigned short* wt = (unsigned short*)(ws + 16777216);
    float* biases = (float*)(ws + 16982016);
    float* coefi = (float*)(ws + 16985600);
    float* g0i = (float*)(ws + 21179904);
    float* g1i = (float*)(ws + 21704192);
    float* g2i = (float*)(ws + 25898496);
    float* g3i = (float*)d_out;

    prep_kernel<<<404, 256, 0, stream>>>(W[0], W[1], W[2], W[3], W[4], W[5], W[6],
                                         B[0], B[1], B[2], B[3], B[4], B[5], B[6],
                                         wt, biases);

    bool fast = ws_size >= 59452928ull;
    if (fast) {
        ileave_kernel<64><<<1024, 256, 0, stream>>>(coef, coefi);
        ileave_kernel<32><<<128, 256, 0, stream>>>(g0, g0i);
        ileave_kernel<64><<<1024, 256, 0, stream>>>(g1, g1i);
        ileave_kernel<128><<<8192, 256, 0, stream>>>(g2, g2i);
        ileave_kernel<256><<<65536, 256, 0, stream>>>(g3, g3i);
        feat_i_kernel<<<N_PTS / 256, 256, 0, stream>>>(x, g0i, g1i, g2i, g3i,
                                                       coefi, feats);
    } else {
        feat_s_kernel<<<N_PTS / 256, 256, 0, stream>>>(x, g0, g1, g2, g3, coef,
                                                       feats);
    }

    mlp_kernel<<<N_PTS / 256, 512, 0, stream>>>(feats, wt, biases, (float*)d_out);
}